// Round 2
// baseline (172.065 us; speedup 1.0000x reference)
//
#include <hip/hip_runtime.h>

#define FEAT 1024
#define TREE_DEPTH 10

typedef float f32x4 __attribute__((ext_vector_type(4)));

// One wave (64 lanes) per sample; 4 waves per 256-thread block.
// Each lane owns 16 floats (4x float4) of x / y-acc at chunk index (lane + 64k).
// Latency fix: per level, issue loads of Y[cur] AND BOTH child X rows before
// the (register-only) dot + butterfly; select the taken child afterward with
// cndmask. Global-load latency is thus overlapped with ~250 cycles of compute
// instead of sitting on the critical path.
// oldx/out are touched once -> non-temporal, keeping L2 for the X/Y gather set.
__global__ __launch_bounds__(256) void fff_kernel(
    const float* __restrict__ x,
    const float* __restrict__ Xw,
    const float* __restrict__ Yw,
    float* __restrict__ out,
    int nsamples)
{
    const int wave = threadIdx.x >> 6;
    const int lane = threadIdx.x & 63;
    const int s = blockIdx.x * 4 + wave;
    if (s >= nsamples) return;

    const float* xp = x + (size_t)s * FEAT;

    f32x4 xv[4], xc[4], acc[4];
#pragma unroll
    for (int k = 0; k < 4; ++k) {
        xv[k] = __builtin_nontemporal_load(
            reinterpret_cast<const f32x4*>(xp + (lane + 64 * k) * 4));
        acc[k] = (f32x4)(0.f);
        // prologue: everyone starts at node 0
        xc[k] = *reinterpret_cast<const f32x4*>(Xw + (lane + 64 * k) * 4);
    }

    int cur = 0;
#pragma unroll
    for (int d = 0; d < TREE_DEPTH; ++d) {
        // Issue Y[cur] loads now; consumed only after the reduce.
        const float* Yp = Yw + (size_t)cur * FEAT;
        f32x4 yv[4];
#pragma unroll
        for (int k = 0; k < 4; ++k)
            yv[k] = *reinterpret_cast<const f32x4*>(Yp + (lane + 64 * k) * 4);

        // Issue BOTH child X rows now (addresses known before the reduce).
        f32x4 xl[4], xr[4];
        if (d < TREE_DEPTH - 1) {
            const float* Xl = Xw + (size_t)(2 * cur + 1) * FEAT;
            const float* Xr = Xw + (size_t)(2 * cur + 2) * FEAT;
#pragma unroll
            for (int k = 0; k < 4; ++k) {
                xl[k] = *reinterpret_cast<const f32x4*>(Xl + (lane + 64 * k) * 4);
                xr[k] = *reinterpret_cast<const f32x4*>(Xr + (lane + 64 * k) * 4);
            }
        }

        // In-lane dot in double: 4 independent chains (branch-decision accuracy).
        double p0 = 0.0, p1 = 0.0, p2 = 0.0, p3 = 0.0;
#pragma unroll
        for (int k = 0; k < 4; ++k) {
            p0 += (double)xv[k][0] * (double)xc[k][0];
            p1 += (double)xv[k][1] * (double)xc[k][1];
            p2 += (double)xv[k][2] * (double)xc[k][2];
            p3 += (double)xv[k][3] * (double)xc[k][3];
        }
        double p = (p0 + p1) + (p2 + p3);

        // 64-lane butterfly (wave = 64 on CDNA).
#pragma unroll
        for (int off = 32; off >= 1; off >>= 1)
            p += __shfl_xor(p, off, 64);

        const float lam = (float)p;
#pragma unroll
        for (int k = 0; k < 4; ++k)
            acc[k] += lam * yv[k];

        const bool right = (p > 0.0);
        cur = 2 * cur + 1 + (right ? 1 : 0);
        if (d < TREE_DEPTH - 1) {
#pragma unroll
            for (int k = 0; k < 4; ++k)
                xc[k] = right ? xr[k] : xl[k];
        }
    }

    float* op = out + (size_t)s * FEAT;
#pragma unroll
    for (int k = 0; k < 4; ++k)
        __builtin_nontemporal_store(acc[k],
            reinterpret_cast<f32x4*>(op + (lane + 64 * k) * 4));
}

extern "C" void kernel_launch(void* const* d_in, const int* in_sizes, int n_in,
                              void* d_out, int out_size, void* d_ws, size_t ws_size,
                              hipStream_t stream) {
    const float* oldx = (const float*)d_in[0];
    const float* Xw   = (const float*)d_in[1];
    const float* Yw   = (const float*)d_in[2];
    float* out = (float*)d_out;

    const int nsamples = in_sizes[0] / FEAT;          // 32768
    const int blocks = (nsamples + 3) / 4;            // 4 samples per block

    fff_kernel<<<blocks, 256, 0, stream>>>(oldx, Xw, Yw, out, nsamples);
}

// Round 3
// 122.717 us; speedup vs baseline: 1.4021x; 1.4021x over previous
//
#include <hip/hip_runtime.h>

#define FEAT 1024
#define DEPTH 10
#define NLEAF 1024          // 2^DEPTH
#define NODES (NLEAF - 1)   // 1023

typedef float f32x4 __attribute__((ext_vector_type(4)));

// ---------------- Pass 1: path. One wave per sample. ----------------
__global__ __launch_bounds__(256) void path_kernel(
    const float* __restrict__ x,
    const float* __restrict__ Xw,
    float* __restrict__ lam_out,
    int* __restrict__ leaf_out,
    int* __restrict__ counts,
    int nsamples)
{
    const int wave = threadIdx.x >> 6;
    const int lane = threadIdx.x & 63;
    const int s = blockIdx.x * 4 + wave;
    if (s >= nsamples) return;

    const float* xp = x + (size_t)s * FEAT;
    f32x4 xv[4];
#pragma unroll
    for (int k = 0; k < 4; ++k)
        xv[k] = __builtin_nontemporal_load(
            reinterpret_cast<const f32x4*>(xp + (lane + 64 * k) * 4));

    int cur = 0;
#pragma unroll
    for (int d = 0; d < DEPTH; ++d) {
        const float* Xr = Xw + (size_t)cur * FEAT;
        double p0 = 0.0, p1 = 0.0, p2 = 0.0, p3 = 0.0;
#pragma unroll
        for (int k = 0; k < 4; ++k) {
            f32x4 xc = *reinterpret_cast<const f32x4*>(Xr + (lane + 64 * k) * 4);
            p0 += (double)xv[k][0] * (double)xc[0];
            p1 += (double)xv[k][1] * (double)xc[1];
            p2 += (double)xv[k][2] * (double)xc[2];
            p3 += (double)xv[k][3] * (double)xc[3];
        }
        double p = (p0 + p1) + (p2 + p3);
#pragma unroll
        for (int off = 32; off >= 1; off >>= 1)
            p += __shfl_xor(p, off, 64);

        if (lane == 0) lam_out[(size_t)s * DEPTH + d] = (float)p;
        cur = 2 * cur + 1 + (p > 0.0 ? 1 : 0);
    }

    if (lane == 0) {
        leaf_out[s] = cur;                       // in [1023, 2046]
        atomicAdd(&counts[cur - NODES], 1);
    }
}

// ---------------- exclusive scan over 1024 leaf counts ----------------
__global__ __launch_bounds__(1024) void scan_kernel(
    const int* __restrict__ counts, int* __restrict__ offs, int* __restrict__ cursor)
{
    __shared__ int a[NLEAF], b[NLEAF];
    const int t = threadIdx.x;
    a[t] = counts[t];
    __syncthreads();
    int* src = a; int* dst = b;
#pragma unroll
    for (int off = 1; off < NLEAF; off <<= 1) {
        dst[t] = (t >= off) ? (src[t] + src[t - off]) : src[t];
        __syncthreads();
        int* tmp = src; src = dst; dst = tmp;
    }
    const int excl = (t == 0) ? 0 : src[t - 1];
    offs[t] = excl;
    cursor[t] = excl;
}

// ---------------- scatter sample ids into leaf-sorted order ----------------
__global__ __launch_bounds__(256) void scatter_kernel(
    const int* __restrict__ leaf, int* __restrict__ cursor,
    int* __restrict__ order, int nsamples)
{
    int i = blockIdx.x * 256 + threadIdx.x;
    if (i < nsamples) {
        const int b = leaf[i] - NODES;
        const int pos = atomicAdd(&cursor[b], 1);
        order[pos] = i;
    }
}

// ---------------- Pass 2: emit. One block per leaf. ----------------
__global__ __launch_bounds__(256) void emit_kernel(
    const float* __restrict__ Yw,
    const float* __restrict__ lam,
    const int* __restrict__ order,
    const int* __restrict__ offs,
    const int* __restrict__ counts,
    float* __restrict__ out)
{
    __shared__ float ylds[DEPTH][FEAT];
    const int b = blockIdx.x;
    const int leafPlus = b + NLEAF;              // (final cur) + 1

#pragma unroll
    for (int d = 0; d < DEPTH; ++d) {
        const int node = (leafPlus >> (DEPTH - d)) - 1;
        reinterpret_cast<f32x4*>(ylds[d])[threadIdx.x] =
            reinterpret_cast<const f32x4*>(Yw + (size_t)node * FEAT)[threadIdx.x];
    }
    __syncthreads();

    const int start = offs[b];
    const int cnt = counts[b];
    const int wave = threadIdx.x >> 6;
    const int lane = threadIdx.x & 63;

    for (int i = wave; i < cnt; i += 4) {
        const int s = order[start + i];
        float lm[DEPTH];
#pragma unroll
        for (int d = 0; d < DEPTH; ++d)
            lm[d] = lam[(size_t)s * DEPTH + d];

        float* op = out + (size_t)s * FEAT;
#pragma unroll
        for (int k = 0; k < 4; ++k) {
            f32x4 o = (f32x4)(0.f);
#pragma unroll
            for (int d = 0; d < DEPTH; ++d)
                o += lm[d] * reinterpret_cast<const f32x4*>(ylds[d])[lane + 64 * k];
            __builtin_nontemporal_store(o, reinterpret_cast<f32x4*>(op + 4 * (lane + 64 * k)));
        }
    }
}

// ---------------- Fallback (R1 single kernel) if ws too small ----------------
__global__ __launch_bounds__(256) void fff_fallback(
    const float* __restrict__ x, const float* __restrict__ Xw,
    const float* __restrict__ Yw, float* __restrict__ out, int nsamples)
{
    const int wave = threadIdx.x >> 6, lane = threadIdx.x & 63;
    const int s = blockIdx.x * 4 + wave;
    if (s >= nsamples) return;
    const float* xp = x + (size_t)s * FEAT;
    f32x4 xv[4], acc[4];
#pragma unroll
    for (int k = 0; k < 4; ++k) {
        xv[k] = *reinterpret_cast<const f32x4*>(xp + (lane + 64 * k) * 4);
        acc[k] = (f32x4)(0.f);
    }
    int cur = 0;
#pragma unroll
    for (int d = 0; d < DEPTH; ++d) {
        const float* Xr = Xw + (size_t)cur * FEAT;
        double p = 0.0;
#pragma unroll
        for (int k = 0; k < 4; ++k) {
            f32x4 xc = *reinterpret_cast<const f32x4*>(Xr + (lane + 64 * k) * 4);
            p += (double)xv[k][0] * (double)xc[0];
            p += (double)xv[k][1] * (double)xc[1];
            p += (double)xv[k][2] * (double)xc[2];
            p += (double)xv[k][3] * (double)xc[3];
        }
#pragma unroll
        for (int off = 32; off >= 1; off >>= 1) p += __shfl_xor(p, off, 64);
        const float lamv = (float)p;
        const float* Yr = Yw + (size_t)cur * FEAT;
#pragma unroll
        for (int k = 0; k < 4; ++k) {
            f32x4 yc = *reinterpret_cast<const f32x4*>(Yr + (lane + 64 * k) * 4);
            acc[k] += lamv * yc;
        }
        cur = 2 * cur + 1 + (p > 0.0 ? 1 : 0);
    }
    float* op = out + (size_t)s * FEAT;
#pragma unroll
    for (int k = 0; k < 4; ++k)
        *reinterpret_cast<f32x4*>(op + 4 * (lane + 64 * k)) = acc[k];
}

extern "C" void kernel_launch(void* const* d_in, const int* in_sizes, int n_in,
                              void* d_out, int out_size, void* d_ws, size_t ws_size,
                              hipStream_t stream) {
    const float* oldx = (const float*)d_in[0];
    const float* Xw   = (const float*)d_in[1];
    const float* Yw   = (const float*)d_in[2];
    float* out = (float*)d_out;

    const int ns = in_sizes[0] / FEAT;           // 32768

    const size_t lamB  = (size_t)ns * DEPTH * sizeof(float);
    const size_t leafB = (size_t)ns * sizeof(int);
    const size_t cntB  = NLEAF * sizeof(int);
    const size_t need  = lamB + leafB + 3 * cntB + leafB;

    if (ws_size < need) {
        fff_fallback<<<(ns + 3) / 4, 256, 0, stream>>>(oldx, Xw, Yw, out, ns);
        return;
    }

    char* w = (char*)d_ws;
    float* lam    = (float*)w;  w += lamB;
    int*   leaf   = (int*)w;    w += leafB;
    int*   counts = (int*)w;    w += cntB;
    int*   offs   = (int*)w;    w += cntB;
    int*   cursor = (int*)w;    w += cntB;
    int*   order  = (int*)w;

    hipMemsetAsync(counts, 0, cntB, stream);
    path_kernel<<<(ns + 3) / 4, 256, 0, stream>>>(oldx, Xw, lam, leaf, counts, ns);
    scan_kernel<<<1, 1024, 0, stream>>>(counts, offs, cursor);
    scatter_kernel<<<(ns + 255) / 256, 256, 0, stream>>>(leaf, cursor, order, ns);
    emit_kernel<<<NLEAF, 256, 0, stream>>>(Yw, lam, order, offs, counts, out);
}